// Round 3
// baseline (2504.944 us; speedup 1.0000x reference)
//
#include <hip/hip_runtime.h>
#include <hip/hip_bf16.h>
#include <math.h>

static __device__ __forceinline__ float sigm(float x) { return 1.0f / (1.0f + expf(-x)); }

template <bool BF>
static __device__ __forceinline__ float ldv(const void* p, int idx) {
    if (BF) return __bfloat162float(((const __hip_bfloat16*)p)[idx]);
    return ((const float*)p)[idx];
}
template <bool BF>
static __device__ __forceinline__ void stv(void* p, int idx, float v) {
    if (BF) ((__hip_bfloat16*)p)[idx] = __float2bfloat16(v);
    else    ((float*)p)[idx] = v;
}

// ---------------- fused map pipeline ----------------
// om[b,128,128] = max3x3(inc) + inc2 where
//   u    = bilinear-align-corners 2x upsample of in_map (pre-sigmoid)
//   inc  = sigmoid(max3x3(u)) - sigmoid(u)        (sigmoid monotone => dilate commutes)
//   inc2 = sigmoid(1 - min3x3(u)) - sigmoid(1-u)
// max/min SAME w/ -inf pad => out-of-image neighbors excluded.
__global__ __launch_bounds__(256) void k_maps(const float* __restrict__ in_map,
                                              float* __restrict__ om) {
    __shared__ float s_u[20][20];     // u tile, halo 2
    __shared__ float s_inc[18][18];   // inc tile, halo 1 (-inf where center invalid)
    int tid = threadIdx.x;
    int b = blockIdx.z;
    int ty0 = (blockIdx.x >> 3) << 4, tx0 = (blockIdx.x & 7) << 4;   // 8x8 tiles of 16x16
    const float* p = in_map + (b << 12);
    const float s = 63.0f / 127.0f;
    for (int e = tid; e < 400; e += 256) {
        int yy = e / 20, xx = e % 20;
        int gy = ty0 + yy - 2, gx = tx0 + xx - 2;
        float v = 0.0f;
        if ((unsigned)gy < 128u && (unsigned)gx < 128u) {
            float cy = gy * s, cx = gx * s;
            int iy0 = (int)cy, ix0 = (int)cx;          // gy,gx >= 0: trunc == floor
            float wy = cy - (float)iy0, wx = cx - (float)ix0;
            int iy1 = min(iy0 + 1, 63), ix1 = min(ix0 + 1, 63);
            float v00 = p[(iy0 << 6) + ix0], v01 = p[(iy0 << 6) + ix1];
            float v10 = p[(iy1 << 6) + ix0], v11 = p[(iy1 << 6) + ix1];
            v = (1.0f - wy) * ((1.0f - wx) * v00 + wx * v01) +
                wy          * ((1.0f - wx) * v10 + wx * v11);
        }
        s_u[yy][xx] = v;
    }
    __syncthreads();
    for (int e = tid; e < 324; e += 256) {
        int yy = e / 18, xx = e % 18;
        int gy = ty0 + yy - 1, gx = tx0 + xx - 1;
        float val = -INFINITY;
        if ((unsigned)gy < 128u && (unsigned)gx < 128u) {
            float uc = s_u[yy + 1][xx + 1];
            float mx = -INFINITY;
            for (int dy = -1; dy <= 1; ++dy) {
                int ny = gy + dy; if ((unsigned)ny >= 128u) continue;
                for (int dx = -1; dx <= 1; ++dx) {
                    int nx = gx + dx; if ((unsigned)nx >= 128u) continue;
                    mx = fmaxf(mx, s_u[yy + 1 + dy][xx + 1 + dx]);
                }
            }
            val = sigm(mx) - sigm(uc);
        }
        s_inc[yy][xx] = val;
    }
    __syncthreads();
    int row = tid >> 4, col = tid & 15;
    int gy = ty0 + row, gx = tx0 + col;
    float mx = -INFINITY;
    #pragma unroll
    for (int dy = 0; dy < 3; ++dy)
        #pragma unroll
        for (int dx = 0; dx < 3; ++dx)
            mx = fmaxf(mx, s_inc[row + dy][col + dx]);   // invalid neighbors are -inf
    float uc = s_u[row + 2][col + 2];
    float mn = INFINITY;
    for (int dy = -1; dy <= 1; ++dy) {
        int ny = gy + dy; if ((unsigned)ny >= 128u) continue;
        for (int dx = -1; dx <= 1; ++dx) {
            int nx = gx + dx; if ((unsigned)nx >= 128u) continue;
            mn = fminf(mn, s_u[row + 2 + dy][col + 2 + dx]);
        }
    }
    float inc2 = sigm(1.0f - mn) - sigm(1.0f - uc);
    om[(b << 14) + (gy << 7) + gx] = mx + inc2;
}

// ---------------- up-conv 7x7 (128->256) + BN + ReLU + pixel_shuffle(2) ----------------
// in: dep_x [8,128,64,64]  w: [256,128,7,7]  out: dep [8,64,128,128]  (all fp32)
__global__ __launch_bounds__(256) void k_upconv(
    const float* __restrict__ x,
    const float* __restrict__ w,
    const float* __restrict__ cb,
    const float* __restrict__ bnp,   // [4,256] g,b,m,v
    float* __restrict__ dep) {
    __shared__ float s_in[8][22][22];
    __shared__ float s_w[8][49][16];
    int tid = threadIdx.x;
    int wave = tid >> 6, lane = tid & 63;
    int row = lane >> 2, xq = lane & 3;
    int ty0 = (blockIdx.x >> 2) << 4;   // 64/16 = 4 tiles per dim
    int tx0 = (blockIdx.x & 3) << 4;
    int o_base = blockIdx.y << 4;       // 16 out channels per block
    int b = blockIdx.z;
    float acc[4][4] = {};
    for (int c0 = 0; c0 < 128; c0 += 8) {
        for (int e = tid; e < 8 * 484; e += 256) {
            int i = e / 484; int r2 = e - i * 484; int yy = r2 / 22; int xx = r2 - yy * 22;
            int gy = ty0 + yy - 3, gx = tx0 + xx - 3;
            float v = 0.0f;
            if ((unsigned)gy < 64u && (unsigned)gx < 64u)
                v = x[((b * 128 + c0 + i) << 12) + (gy << 6) + gx];
            s_in[i][yy][xx] = v;
        }
        for (int e = tid; e < 8 * 784; e += 256) {
            int i = e / 784; int r2 = e - i * 784; int tap = r2 >> 4; int ol = r2 & 15;
            s_w[i][tap][ol] = w[((o_base + ol) * 128 + c0 + i) * 49 + tap];
        }
        __syncthreads();
        for (int i = 0; i < 8; ++i) {
            #pragma unroll
            for (int dy = 0; dy < 7; ++dy) {
                float a[10];
                #pragma unroll
                for (int q = 0; q < 10; ++q) a[q] = s_in[i][row + dy][xq * 4 + q];
                #pragma unroll
                for (int dx = 0; dx < 7; ++dx) {
                    float w0 = s_w[i][dy * 7 + dx][wave * 4 + 0];
                    float w1 = s_w[i][dy * 7 + dx][wave * 4 + 1];
                    float w2 = s_w[i][dy * 7 + dx][wave * 4 + 2];
                    float w3 = s_w[i][dy * 7 + dx][wave * 4 + 3];
                    #pragma unroll
                    for (int p = 0; p < 4; ++p) {
                        float av = a[dx + p];
                        acc[0][p] = fmaf(w0, av, acc[0][p]);
                        acc[1][p] = fmaf(w1, av, acc[1][p]);
                        acc[2][p] = fmaf(w2, av, acc[2][p]);
                        acc[3][p] = fmaf(w3, av, acc[3][p]);
                    }
                }
            }
        }
        __syncthreads();
    }
    #pragma unroll
    for (int oo = 0; oo < 4; ++oo) {
        int o = o_base + wave * 4 + oo;
        float g  = bnp[o],       bt = bnp[256 + o];
        float m  = bnp[512 + o], vv = bnp[768 + o];
        float scale = g * rsqrtf(vv + 1e-5f);
        float cbf = cb[o];
        int c = o >> 2, sbit = (o >> 1) & 1, tbit = o & 1;
        int y = ty0 + row;
        #pragma unroll
        for (int p = 0; p < 4; ++p) {
            int xc = tx0 + xq * 4 + p;
            float val = (acc[oo][p] + cbf - m) * scale + bt;
            dep[((b * 64 + c) << 14) + ((2 * y + sbit) << 7) + (2 * xc + tbit)] = fmaxf(val, 0.0f);
        }
    }
}

// ---------------- generic 3x3 conv (64->64), two fusion modes ----------------
// MODE 0: out = relu(bn(conv(xin) + cb))                       (d1/d2/d3 layers)
// MODE 1: out = dep + beta*(conv(xin * outmap) + cb)           (conv2 + residual)
template <int MODE, bool INBF, bool OUTBF>
__global__ __launch_bounds__(256) void k_conv3(
    const void* __restrict__ xin,
    const float* __restrict__ om,    // fp32 map (MODE 1 only)
    const float* __restrict__ dep,   // fp32 residual (MODE 1 only)
    const float* __restrict__ w,     // [64,64,3,3]
    const float* __restrict__ cb,    // [64]
    const float* __restrict__ bnp,   // [4,64]
    const float* __restrict__ beta,  // [1]
    void* __restrict__ out) {
    __shared__ float s_in[8][18][18];
    __shared__ float s_w[8][9][16];
    int tid = threadIdx.x;
    int wave = tid >> 6, lane = tid & 63;
    int row = lane >> 2, xq = lane & 3;
    int ty0 = (blockIdx.x >> 3) << 4;   // 128/16 = 8 tiles per dim
    int tx0 = (blockIdx.x & 7) << 4;
    int o_base = blockIdx.y << 4;
    int b = blockIdx.z;
    float acc[4][4] = {};
    for (int c0 = 0; c0 < 64; c0 += 8) {
        for (int e = tid; e < 8 * 324; e += 256) {
            int i = e / 324; int r2 = e - i * 324; int yy = r2 / 18; int xx = r2 - yy * 18;
            int gy = ty0 + yy - 1, gx = tx0 + xx - 1;
            float v = 0.0f;
            if ((unsigned)gy < 128u && (unsigned)gx < 128u) {
                v = ldv<INBF>(xin, ((b * 64 + c0 + i) << 14) + (gy << 7) + gx);
                if (MODE == 1) v *= om[(b << 14) + (gy << 7) + gx];
            }
            s_in[i][yy][xx] = v;
        }
        for (int e = tid; e < 8 * 144; e += 256) {
            int i = e / 144; int r2 = e - i * 144; int tap = r2 >> 4; int ol = r2 & 15;
            s_w[i][tap][ol] = w[((o_base + ol) * 64 + c0 + i) * 9 + tap];
        }
        __syncthreads();
        for (int i = 0; i < 8; ++i) {
            #pragma unroll
            for (int dy = 0; dy < 3; ++dy) {
                float a[6];
                #pragma unroll
                for (int q = 0; q < 6; ++q) a[q] = s_in[i][row + dy][xq * 4 + q];
                #pragma unroll
                for (int dx = 0; dx < 3; ++dx) {
                    float w0 = s_w[i][dy * 3 + dx][wave * 4 + 0];
                    float w1 = s_w[i][dy * 3 + dx][wave * 4 + 1];
                    float w2 = s_w[i][dy * 3 + dx][wave * 4 + 2];
                    float w3 = s_w[i][dy * 3 + dx][wave * 4 + 3];
                    #pragma unroll
                    for (int p = 0; p < 4; ++p) {
                        float av = a[dx + p];
                        acc[0][p] = fmaf(w0, av, acc[0][p]);
                        acc[1][p] = fmaf(w1, av, acc[1][p]);
                        acc[2][p] = fmaf(w2, av, acc[2][p]);
                        acc[3][p] = fmaf(w3, av, acc[3][p]);
                    }
                }
            }
        }
        __syncthreads();
    }
    float betav = (MODE == 1) ? beta[0] : 0.0f;
    #pragma unroll
    for (int oo = 0; oo < 4; ++oo) {
        int o = o_base + wave * 4 + oo;
        float cbf = cb[o];
        float scale = 1.0f, shift = 0.0f;
        if (MODE == 0) {
            float g  = bnp[o],       bt = bnp[64 + o];
            float m  = bnp[128 + o], vv = bnp[192 + o];
            scale = g * rsqrtf(vv + 1e-5f);
            shift = bt - m * scale;
        }
        #pragma unroll
        for (int p = 0; p < 4; ++p) {
            int idx = ((b * 64 + o) << 14) + ((ty0 + row) << 7) + tx0 + xq * 4 + p;
            float val = acc[oo][p] + cbf;
            if (MODE == 0) val = fmaxf(val * scale + shift, 0.0f);
            else           val = dep[idx] + betav * val;
            stv<OUTBF>(out, idx, val);
        }
    }
}

// ---------------- final 7x7 conv (64->1) ----------------
__global__ __launch_bounds__(256) void k_outconv(
    const float* __restrict__ r,    // [8,64,128,128]
    const float* __restrict__ w,    // [64*49]
    const float* __restrict__ ob,   // [1]
    float* __restrict__ out) {      // [8,128,128]
    __shared__ float s_in[8][22][22];
    __shared__ float s_w[64 * 49];
    int tid = threadIdx.x;
    int ty = tid >> 4, tx = tid & 15;
    int ty0 = (blockIdx.x >> 3) << 4, tx0 = (blockIdx.x & 7) << 4;
    int b = blockIdx.z;
    for (int e = tid; e < 64 * 49; e += 256) s_w[e] = w[e];
    float acc = 0.0f;
    for (int c0 = 0; c0 < 64; c0 += 8) {
        __syncthreads();
        for (int e = tid; e < 8 * 484; e += 256) {
            int i = e / 484; int r2 = e - i * 484; int yy = r2 / 22; int xx = r2 - yy * 22;
            int gy = ty0 + yy - 3, gx = tx0 + xx - 3;
            float v = 0.0f;
            if ((unsigned)gy < 128u && (unsigned)gx < 128u)
                v = r[((b * 64 + c0 + i) << 14) + (gy << 7) + gx];
            s_in[i][yy][xx] = v;
        }
        __syncthreads();
        for (int i = 0; i < 8; ++i) {
            #pragma unroll
            for (int dy = 0; dy < 7; ++dy)
                #pragma unroll
                for (int dx = 0; dx < 7; ++dx)
                    acc = fmaf(s_in[i][ty + dy][tx + dx], s_w[(c0 + i) * 49 + dy * 7 + dx], acc);
        }
    }
    out[(b << 14) + ((ty0 + ty) << 7) + tx0 + tx] = acc + ob[0];
}

extern "C" void kernel_launch(void* const* d_in, const int* in_sizes, int n_in,
                              void* d_out, int out_size, void* d_ws, size_t ws_size,
                              hipStream_t stream) {
    const float* cur_x  = (const float*)d_in[0];
    const float* dep_x  = (const float*)d_in[1];
    const float* in_map = (const float*)d_in[2];
    const float* up_w   = (const float*)d_in[3];
    const float* up_b   = (const float*)d_in[4];
    const float* up_bn  = (const float*)d_in[5];
    const float* c2_w   = (const float*)d_in[6];
    const float* c2_b   = (const float*)d_in[7];
    const float* d1_w   = (const float*)d_in[8];
    const float* d1_b   = (const float*)d_in[9];
    const float* d1_bn  = (const float*)d_in[10];
    const float* d2_w   = (const float*)d_in[11];
    const float* d2_b   = (const float*)d_in[12];
    const float* d2_bn  = (const float*)d_in[13];
    const float* d3_w   = (const float*)d_in[14];
    const float* d3_b   = (const float*)d_in[15];
    const float* d3_bn  = (const float*)d_in[16];
    const float* out_w  = (const float*)d_in[17];
    const float* out_b  = (const float*)d_in[18];
    const float* beta   = (const float*)d_in[19];

    // Buffer plan (ws footprint = 16.8 MiB only):
    //   r_out   = d_out[0 .. 8388608) fp32     : dep -> r1 -> r (final)
    //   om      = d_out[8388608 ..]   fp32     : map (131072 floats = exactly map_out
    //                                            region), consumed by conv2, then
    //                                            overwritten by the final outconv
    //   W1      = d_ws, bf16 8388608 elements  : t -> r2
    float* r_out = (float*)d_out;
    float* om    = r_out + 8388608;
    void*  W1    = d_ws;

    k_maps<<<dim3(64, 1, 8), 256, 0, stream>>>(in_map, om);
    // dep = pixel_shuffle(relu(bn(conv7x7(dep_x))))  -> r_out
    k_upconv<<<dim3(16, 16, 8), 256, 0, stream>>>(dep_x, up_w, up_b, up_bn, r_out);
    // t = dep + beta * (conv3x3(om*cur_x) + c2_b)    -> W1 (bf16)
    k_conv3<1, false, true><<<dim3(64, 4, 8), 256, 0, stream>>>(
        cur_x, om, r_out, c2_w, c2_b, nullptr, beta, W1);
    // r1 -> r_out (fp32)
    k_conv3<0, true, false><<<dim3(64, 4, 8), 256, 0, stream>>>(
        W1, nullptr, nullptr, d1_w, d1_b, d1_bn, nullptr, r_out);
    // r2 -> W1 (bf16)
    k_conv3<0, false, true><<<dim3(64, 4, 8), 256, 0, stream>>>(
        r_out, nullptr, nullptr, d2_w, d2_b, d2_bn, nullptr, W1);
    // r (final) -> r_out (fp32)
    k_conv3<0, true, false><<<dim3(64, 4, 8), 256, 0, stream>>>(
        W1, nullptr, nullptr, d3_w, d3_b, d3_bn, nullptr, r_out);
    // output_map = conv7x7(r) + out_b -> map_out (overwrites om)
    k_outconv<<<dim3(64, 1, 8), 256, 0, stream>>>(r_out, out_w, out_b, om);
}

// Round 4
// 1218.420 us; speedup vs baseline: 2.0559x; 2.0559x over previous
//
#include <hip/hip_runtime.h>
#include <hip/hip_bf16.h>
#include <math.h>

static __device__ __forceinline__ float sigm(float x) { return 1.0f / (1.0f + expf(-x)); }

// fp32 -> bf16 bits, round-to-nearest-even
static __device__ __forceinline__ short f2bf_s(float f) {
    unsigned u = __float_as_uint(f);
    u += 0x7fffu + ((u >> 16) & 1u);
    return (short)(u >> 16);
}

typedef __attribute__((ext_vector_type(8))) short short8;
typedef __attribute__((ext_vector_type(4))) float f32x4;

template <bool BF>
static __device__ __forceinline__ float ldv(const void* p, int idx) {
    if (BF) return __bfloat162float(((const __hip_bfloat16*)p)[idx]);
    return ((const float*)p)[idx];
}
template <bool BF>
static __device__ __forceinline__ void stv(void* p, int idx, float v) {
    if (BF) ((__hip_bfloat16*)p)[idx] = __float2bfloat16(v);
    else    ((float*)p)[idx] = v;
}

// ---------------- fused map pipeline (unchanged, verified) ----------------
__global__ __launch_bounds__(256) void k_maps(const float* __restrict__ in_map,
                                              float* __restrict__ om) {
    __shared__ float s_u[20][20];
    __shared__ float s_inc[18][18];
    int tid = threadIdx.x;
    int b = blockIdx.z;
    int ty0 = (blockIdx.x >> 3) << 4, tx0 = (blockIdx.x & 7) << 4;
    const float* p = in_map + (b << 12);
    const float s = 63.0f / 127.0f;
    for (int e = tid; e < 400; e += 256) {
        int yy = e / 20, xx = e % 20;
        int gy = ty0 + yy - 2, gx = tx0 + xx - 2;
        float v = 0.0f;
        if ((unsigned)gy < 128u && (unsigned)gx < 128u) {
            float cy = gy * s, cx = gx * s;
            int iy0 = (int)cy, ix0 = (int)cx;
            float wy = cy - (float)iy0, wx = cx - (float)ix0;
            int iy1 = min(iy0 + 1, 63), ix1 = min(ix0 + 1, 63);
            float v00 = p[(iy0 << 6) + ix0], v01 = p[(iy0 << 6) + ix1];
            float v10 = p[(iy1 << 6) + ix0], v11 = p[(iy1 << 6) + ix1];
            v = (1.0f - wy) * ((1.0f - wx) * v00 + wx * v01) +
                wy          * ((1.0f - wx) * v10 + wx * v11);
        }
        s_u[yy][xx] = v;
    }
    __syncthreads();
    for (int e = tid; e < 324; e += 256) {
        int yy = e / 18, xx = e % 18;
        int gy = ty0 + yy - 1, gx = tx0 + xx - 1;
        float val = -INFINITY;
        if ((unsigned)gy < 128u && (unsigned)gx < 128u) {
            float uc = s_u[yy + 1][xx + 1];
            float mx = -INFINITY;
            for (int dy = -1; dy <= 1; ++dy) {
                int ny = gy + dy; if ((unsigned)ny >= 128u) continue;
                for (int dx = -1; dx <= 1; ++dx) {
                    int nx = gx + dx; if ((unsigned)nx >= 128u) continue;
                    mx = fmaxf(mx, s_u[yy + 1 + dy][xx + 1 + dx]);
                }
            }
            val = sigm(mx) - sigm(uc);
        }
        s_inc[yy][xx] = val;
    }
    __syncthreads();
    int row = tid >> 4, col = tid & 15;
    int gy = ty0 + row, gx = tx0 + col;
    float mx = -INFINITY;
    #pragma unroll
    for (int dy = 0; dy < 3; ++dy)
        #pragma unroll
        for (int dx = 0; dx < 3; ++dx)
            mx = fmaxf(mx, s_inc[row + dy][col + dx]);
    float uc = s_u[row + 2][col + 2];
    float mn = INFINITY;
    for (int dy = -1; dy <= 1; ++dy) {
        int ny = gy + dy; if ((unsigned)ny >= 128u) continue;
        for (int dx = -1; dx <= 1; ++dx) {
            int nx = gx + dx; if ((unsigned)nx >= 128u) continue;
            mn = fminf(mn, s_u[row + 2 + dy][col + 2 + dx]);
        }
    }
    float inc2 = sigm(1.0f - mn) - sigm(1.0f - uc);
    om[(b << 14) + (gy << 7) + gx] = mx + inc2;
}

// ---------------- weight prep: up_w fp32 [256][128][7][7] -> bf16 wb ----------------
// wb[nt 4][cc 4][dy 7][dx 7][o 64][c 32], linear W = ((((nt*4+cc)*7+dy)*7+dx)*64+o)*32+c
__global__ __launch_bounds__(256) void k_prepw(const float* __restrict__ w,
                                               short* __restrict__ wb) {
    int s = blockIdx.x * 256 + threadIdx.x;   // source-linear, coalesced reads
    if (s >= 1605632) return;
    int O = s / 6272; int r = s - O * 6272;
    int C = r / 49;   int T = r - C * 49;
    int dy = T / 7, dx = T - dy * 7;
    int nt = O >> 6, o = O & 63;
    int cc = C >> 5, c = C & 31;
    int W = ((((nt * 4 + cc) * 7 + dy) * 7 + dx) * 64 + o) * 32 + c;
    wb[W] = f2bf_s(w[s]);
}

// ---------------- up-conv 7x7 (128->256) via MFMA + BN + ReLU + pixel_shuffle ----------------
// Implicit GEMM: M=pixels (tile 8 rows x 16 cols), N=64 out-ch/block, K=32ch x 49 taps x 4 chunks.
// mfma_f32_16x16x32_bf16: A[m=lane&15][k=q*8+j], B[k=q*8+j][n=lane&15], D col=lane&15 row=q*4+reg.
// LDS stride 40 shorts (80B): bank = 4*((5*idx+q)%8) over lanes -> uniform 8 acc/bank, conflict-free.
__global__ __launch_bounds__(256) void k_upconv_mfma(
    const float* __restrict__ x,      // [8,128,64,64]
    const short* __restrict__ wb,     // prepped weights (bf16 bits)
    const float* __restrict__ cb,     // [256]
    const float* __restrict__ bnp,    // [4,256]
    float* __restrict__ dep) {        // [8,64,128,128]
    __shared__ __attribute__((aligned(16))) short s_in[308 * 40];  // 14x22 cells
    __shared__ __attribute__((aligned(16))) short s_w[448 * 40];   // 7dx x 64o rows
    int tid = threadIdx.x;
    int wave = tid >> 6, lane = tid & 63;
    int q = lane >> 4, m = lane & 15;
    int mw = wave >> 1, nw = wave & 1;
    int ty0 = (blockIdx.x >> 2) * 8;      // 8 y-tiles of 8 rows
    int tx0 = (blockIdx.x & 3) * 16;      // 4 x-tiles of 16 cols
    int nt = blockIdx.y;                  // 4 n-tiles of 64 out-ch
    int b = blockIdx.z;
    f32x4 acc[4][2];
    #pragma unroll
    for (int i = 0; i < 4; ++i)
        #pragma unroll
        for (int j = 0; j < 2; ++j)
            acc[i][j] = (f32x4){0.f, 0.f, 0.f, 0.f};
    const float* xb = x + ((long)(b * 128) << 12);
    for (int cc = 0; cc < 4; ++cc) {
        __syncthreads();   // previous-iter readers of s_in done
        // stage input chunk (32 channels) as [cell][c], cell-fastest for coalescing
        for (int e = tid; e < 1232; e += 256) {
            int cq = e / 308; int cell = e - cq * 308;
            int yy = cell / 22, xx = cell - yy * 22;
            int gy = ty0 + yy - 3, gx = tx0 + xx - 3;
            float v[8];
            if ((unsigned)gy < 64u && (unsigned)gx < 64u) {
                const float* src = xb + (((cc * 32 + cq * 8)) << 12) + (gy << 6) + gx;
                #pragma unroll
                for (int j2 = 0; j2 < 8; ++j2) v[j2] = src[j2 << 12];
            } else {
                #pragma unroll
                for (int j2 = 0; j2 < 8; ++j2) v[j2] = 0.0f;
            }
            short8 pk;
            #pragma unroll
            for (int j2 = 0; j2 < 8; ++j2) pk[j2] = f2bf_s(v[j2]);
            *(short8*)&s_in[cell * 40 + cq * 8] = pk;
        }
        for (int dy = 0; dy < 7; ++dy) {
            __syncthreads();   // previous-dy readers of s_w done (also fences s_in stage on dy==0)
            const short* wsl = wb + (((nt * 4 + cc) * 7 + dy) * 7) * 2048;
            for (int e = tid; e < 1792; e += 256) {       // 7dx*64o rows x 4 cq
                int row = e >> 2, cq = e & 3;
                short8 pk = *(const short8*)&wsl[row * 32 + cq * 8];
                *(short8*)&s_w[row * 40 + cq * 8] = pk;
            }
            __syncthreads();
            #pragma unroll
            for (int dx = 0; dx < 7; ++dx) {
                short8 a[4], bf[2];
                #pragma unroll
                for (int i = 0; i < 4; ++i) {
                    int cell = (mw * 4 + i + dy) * 22 + (m + dx);
                    a[i] = *(const short8*)&s_in[cell * 40 + q * 8];
                }
                #pragma unroll
                for (int j = 0; j < 2; ++j) {
                    int row = dx * 64 + (nw * 2 + j) * 16 + m;
                    bf[j] = *(const short8*)&s_w[row * 40 + q * 8];
                }
                #pragma unroll
                for (int i = 0; i < 4; ++i)
                    #pragma unroll
                    for (int j = 0; j < 2; ++j)
                        acc[i][j] = __builtin_amdgcn_mfma_f32_16x16x32_bf16(
                            a[i], bf[j], acc[i][j], 0, 0, 0);
            }
        }
    }
    // epilogue: bias + BN + ReLU + pixel-shuffle scatter (fp32)
    #pragma unroll
    for (int j = 0; j < 2; ++j) {
        int o = nt * 64 + (nw * 2 + j) * 16 + m;
        float g  = bnp[o],       bt = bnp[256 + o];
        float mn = bnp[512 + o], vv = bnp[768 + o];
        float scale = g * rsqrtf(vv + 1e-5f);
        float cbf = cb[o];
        int c = o >> 2, sbit = (o >> 1) & 1, tbit = o & 1;
        #pragma unroll
        for (int i = 0; i < 4; ++i) {
            int y = ty0 + mw * 4 + i;
            #pragma unroll
            for (int reg = 0; reg < 4; ++reg) {
                int xc = tx0 + q * 4 + reg;
                float val = (acc[i][j][reg] + cbf - mn) * scale + bt;
                val = fmaxf(val, 0.0f);
                dep[((b * 64 + c) << 14) + ((2 * y + sbit) << 7) + (2 * xc + tbit)] = val;
            }
        }
    }
}

// ---------------- generic 3x3 conv (64->64), two fusion modes (unchanged) ----------------
template <int MODE, bool INBF, bool OUTBF>
__global__ __launch_bounds__(256) void k_conv3(
    const void* __restrict__ xin,
    const float* __restrict__ om,
    const float* __restrict__ dep,
    const float* __restrict__ w,
    const float* __restrict__ cb,
    const float* __restrict__ bnp,
    const float* __restrict__ beta,
    void* __restrict__ out) {
    __shared__ float s_in[8][18][18];
    __shared__ float s_w[8][9][16];
    int tid = threadIdx.x;
    int wave = tid >> 6, lane = tid & 63;
    int row = lane >> 2, xq = lane & 3;
    int ty0 = (blockIdx.x >> 3) << 4;
    int tx0 = (blockIdx.x & 7) << 4;
    int o_base = blockIdx.y << 4;
    int b = blockIdx.z;
    float acc[4][4] = {};
    for (int c0 = 0; c0 < 64; c0 += 8) {
        for (int e = tid; e < 8 * 324; e += 256) {
            int i = e / 324; int r2 = e - i * 324; int yy = r2 / 18; int xx = r2 - yy * 18;
            int gy = ty0 + yy - 1, gx = tx0 + xx - 1;
            float v = 0.0f;
            if ((unsigned)gy < 128u && (unsigned)gx < 128u) {
                v = ldv<INBF>(xin, ((b * 64 + c0 + i) << 14) + (gy << 7) + gx);
                if (MODE == 1) v *= om[(b << 14) + (gy << 7) + gx];
            }
            s_in[i][yy][xx] = v;
        }
        for (int e = tid; e < 8 * 144; e += 256) {
            int i = e / 144; int r2 = e - i * 144; int tap = r2 >> 4; int ol = r2 & 15;
            s_w[i][tap][ol] = w[((o_base + ol) * 64 + c0 + i) * 9 + tap];
        }
        __syncthreads();
        for (int i = 0; i < 8; ++i) {
            #pragma unroll
            for (int dy = 0; dy < 3; ++dy) {
                float a[6];
                #pragma unroll
                for (int qq = 0; qq < 6; ++qq) a[qq] = s_in[i][row + dy][xq * 4 + qq];
                #pragma unroll
                for (int dx = 0; dx < 3; ++dx) {
                    float w0 = s_w[i][dy * 3 + dx][wave * 4 + 0];
                    float w1 = s_w[i][dy * 3 + dx][wave * 4 + 1];
                    float w2 = s_w[i][dy * 3 + dx][wave * 4 + 2];
                    float w3 = s_w[i][dy * 3 + dx][wave * 4 + 3];
                    #pragma unroll
                    for (int p = 0; p < 4; ++p) {
                        float av = a[dx + p];
                        acc[0][p] = fmaf(w0, av, acc[0][p]);
                        acc[1][p] = fmaf(w1, av, acc[1][p]);
                        acc[2][p] = fmaf(w2, av, acc[2][p]);
                        acc[3][p] = fmaf(w3, av, acc[3][p]);
                    }
                }
            }
        }
        __syncthreads();
    }
    float betav = (MODE == 1) ? beta[0] : 0.0f;
    #pragma unroll
    for (int oo = 0; oo < 4; ++oo) {
        int o = o_base + wave * 4 + oo;
        float cbf = cb[o];
        float scale = 1.0f, shift = 0.0f;
        if (MODE == 0) {
            float g  = bnp[o],       bt = bnp[64 + o];
            float mm = bnp[128 + o], vv = bnp[192 + o];
            scale = g * rsqrtf(vv + 1e-5f);
            shift = bt - mm * scale;
        }
        #pragma unroll
        for (int p = 0; p < 4; ++p) {
            int idx = ((b * 64 + o) << 14) + ((ty0 + row) << 7) + tx0 + xq * 4 + p;
            float val = acc[oo][p] + cbf;
            if (MODE == 0) val = fmaxf(val * scale + shift, 0.0f);
            else           val = dep[idx] + betav * val;
            stv<OUTBF>(out, idx, val);
        }
    }
}

// ---------------- final 7x7 conv (64->1) (unchanged) ----------------
__global__ __launch_bounds__(256) void k_outconv(
    const float* __restrict__ r,
    const float* __restrict__ w,
    const float* __restrict__ ob,
    float* __restrict__ out) {
    __shared__ float s_in[8][22][22];
    __shared__ float s_w[64 * 49];
    int tid = threadIdx.x;
    int ty = tid >> 4, tx = tid & 15;
    int ty0 = (blockIdx.x >> 3) << 4, tx0 = (blockIdx.x & 7) << 4;
    int b = blockIdx.z;
    for (int e = tid; e < 64 * 49; e += 256) s_w[e] = w[e];
    float acc = 0.0f;
    for (int c0 = 0; c0 < 64; c0 += 8) {
        __syncthreads();
        for (int e = tid; e < 8 * 484; e += 256) {
            int i = e / 484; int r2 = e - i * 484; int yy = r2 / 22; int xx = r2 - yy * 22;
            int gy = ty0 + yy - 3, gx = tx0 + xx - 3;
            float v = 0.0f;
            if ((unsigned)gy < 128u && (unsigned)gx < 128u)
                v = r[((b * 64 + c0 + i) << 14) + (gy << 7) + gx];
            s_in[i][yy][xx] = v;
        }
        __syncthreads();
        for (int i = 0; i < 8; ++i) {
            #pragma unroll
            for (int dy = 0; dy < 7; ++dy)
                #pragma unroll
                for (int dx = 0; dx < 7; ++dx)
                    acc = fmaf(s_in[i][ty + dy][tx + dx], s_w[(c0 + i) * 49 + dy * 7 + dx], acc);
        }
    }
    out[(b << 14) + ((ty0 + ty) << 7) + tx0 + tx] = acc + ob[0];
}

extern "C" void kernel_launch(void* const* d_in, const int* in_sizes, int n_in,
                              void* d_out, int out_size, void* d_ws, size_t ws_size,
                              hipStream_t stream) {
    const float* cur_x  = (const float*)d_in[0];
    const float* dep_x  = (const float*)d_in[1];
    const float* in_map = (const float*)d_in[2];
    const float* up_w   = (const float*)d_in[3];
    const float* up_b   = (const float*)d_in[4];
    const float* up_bn  = (const float*)d_in[5];
    const float* c2_w   = (const float*)d_in[6];
    const float* c2_b   = (const float*)d_in[7];
    const float* d1_w   = (const float*)d_in[8];
    const float* d1_b   = (const float*)d_in[9];
    const float* d1_bn  = (const float*)d_in[10];
    const float* d2_w   = (const float*)d_in[11];
    const float* d2_b   = (const float*)d_in[12];
    const float* d2_bn  = (const float*)d_in[13];
    const float* d3_w   = (const float*)d_in[14];
    const float* d3_b   = (const float*)d_in[15];
    const float* d3_bn  = (const float*)d_in[16];
    const float* out_w  = (const float*)d_in[17];
    const float* out_b  = (const float*)d_in[18];
    const float* beta   = (const float*)d_in[19];

    // Buffer plan (ws footprint = 16.8 MiB, proven safe in round 3):
    //   r_out = d_out[0..8388608) fp32 : dep -> r1 -> r
    //   om    = d_out[8388608..)  fp32 : map, consumed by conv2, overwritten by outconv
    //   W1    = d_ws bf16 x 8388608    : t -> r2
    //   wb    = d_ws head, 3.2 MB bf16 : prepped up_w; consumed by upconv BEFORE
    //                                    conv2 overwrites the region with t (stream-ordered)
    float* r_out = (float*)d_out;
    float* om    = r_out + 8388608;
    void*  W1    = d_ws;
    short* wb    = (short*)d_ws;

    k_maps<<<dim3(64, 1, 8), 256, 0, stream>>>(in_map, om);
    k_prepw<<<6272, 256, 0, stream>>>(up_w, wb);
    // dep = pixel_shuffle(relu(bn(conv7x7(dep_x)))) -> r_out   [MFMA]
    k_upconv_mfma<<<dim3(32, 4, 8), 256, 0, stream>>>(dep_x, wb, up_b, up_bn, r_out);
    // t = dep + beta*(conv3x3(om*cur_x)+c2_b) -> W1 (bf16)
    k_conv3<1, false, true><<<dim3(64, 4, 8), 256, 0, stream>>>(
        cur_x, om, r_out, c2_w, c2_b, nullptr, beta, W1);
    // r1 -> r_out (fp32)
    k_conv3<0, true, false><<<dim3(64, 4, 8), 256, 0, stream>>>(
        W1, nullptr, nullptr, d1_w, d1_b, d1_bn, nullptr, r_out);
    // r2 -> W1 (bf16)
    k_conv3<0, false, true><<<dim3(64, 4, 8), 256, 0, stream>>>(
        r_out, nullptr, nullptr, d2_w, d2_b, d2_bn, nullptr, W1);
    // r (final) -> r_out (fp32)
    k_conv3<0, true, false><<<dim3(64, 4, 8), 256, 0, stream>>>(
        W1, nullptr, nullptr, d3_w, d3_b, d3_bn, nullptr, r_out);
    // output_map = conv7x7(r) + out_b -> map_out (overwrites om)
    k_outconv<<<dim3(64, 1, 8), 256, 0, stream>>>(r_out, out_w, out_b, om);
}

// Round 5
// 571.532 us; speedup vs baseline: 4.3829x; 2.1318x over previous
//
#include <hip/hip_runtime.h>
#include <hip/hip_bf16.h>
#include <math.h>

static __device__ __forceinline__ float sigm(float x) { return 1.0f / (1.0f + expf(-x)); }

// fp32 -> bf16 bits, round-to-nearest-even
static __device__ __forceinline__ short f2bf_s(float f) {
    unsigned u = __float_as_uint(f);
    u += 0x7fffu + ((u >> 16) & 1u);
    return (short)(u >> 16);
}
// bf16 bits -> fp32
static __device__ __forceinline__ float bfb2f(short s) {
    return __uint_as_float(((unsigned)(unsigned short)s) << 16);
}

typedef __attribute__((ext_vector_type(8))) short short8;
typedef __attribute__((ext_vector_type(4))) short short4v;
typedef __attribute__((ext_vector_type(4))) float f32x4;

// ---------------- fused map pipeline -> om (bf16) ----------------
__global__ __launch_bounds__(256) void k_maps(const float* __restrict__ in_map,
                                              short* __restrict__ om_bf) {
    __shared__ float s_u[20][20];
    __shared__ float s_inc[18][18];
    int tid = threadIdx.x;
    int b = blockIdx.z;
    int ty0 = (blockIdx.x >> 3) << 4, tx0 = (blockIdx.x & 7) << 4;
    const float* p = in_map + (b << 12);
    const float s = 63.0f / 127.0f;
    for (int e = tid; e < 400; e += 256) {
        int yy = e / 20, xx = e % 20;
        int gy = ty0 + yy - 2, gx = tx0 + xx - 2;
        float v = 0.0f;
        if ((unsigned)gy < 128u && (unsigned)gx < 128u) {
            float cy = gy * s, cx = gx * s;
            int iy0 = (int)cy, ix0 = (int)cx;
            float wy = cy - (float)iy0, wx = cx - (float)ix0;
            int iy1 = min(iy0 + 1, 63), ix1 = min(ix0 + 1, 63);
            float v00 = p[(iy0 << 6) + ix0], v01 = p[(iy0 << 6) + ix1];
            float v10 = p[(iy1 << 6) + ix0], v11 = p[(iy1 << 6) + ix1];
            v = (1.0f - wy) * ((1.0f - wx) * v00 + wx * v01) +
                wy          * ((1.0f - wx) * v10 + wx * v11);
        }
        s_u[yy][xx] = v;
    }
    __syncthreads();
    for (int e = tid; e < 324; e += 256) {
        int yy = e / 18, xx = e % 18;
        int gy = ty0 + yy - 1, gx = tx0 + xx - 1;
        float val = -INFINITY;
        if ((unsigned)gy < 128u && (unsigned)gx < 128u) {
            float uc = s_u[yy + 1][xx + 1];
            float mx = -INFINITY;
            for (int dy = -1; dy <= 1; ++dy) {
                int ny = gy + dy; if ((unsigned)ny >= 128u) continue;
                for (int dx = -1; dx <= 1; ++dx) {
                    int nx = gx + dx; if ((unsigned)nx >= 128u) continue;
                    mx = fmaxf(mx, s_u[yy + 1 + dy][xx + 1 + dx]);
                }
            }
            val = sigm(mx) - sigm(uc);
        }
        s_inc[yy][xx] = val;
    }
    __syncthreads();
    int row = tid >> 4, col = tid & 15;
    int gy = ty0 + row, gx = tx0 + col;
    float mx = -INFINITY;
    #pragma unroll
    for (int dy = 0; dy < 3; ++dy)
        #pragma unroll
        for (int dx = 0; dx < 3; ++dx)
            mx = fmaxf(mx, s_inc[row + dy][col + dx]);
    float uc = s_u[row + 2][col + 2];
    float mn = INFINITY;
    for (int dy = -1; dy <= 1; ++dy) {
        int ny = gy + dy; if ((unsigned)ny >= 128u) continue;
        for (int dx = -1; dx <= 1; ++dx) {
            int nx = gx + dx; if ((unsigned)nx >= 128u) continue;
            mn = fminf(mn, s_u[row + 2 + dy][col + 2 + dx]);
        }
    }
    float inc2 = sigm(1.0f - mn) - sigm(1.0f - uc);
    om_bf[(b << 14) + (gy << 7) + gx] = f2bf_s(mx + inc2);
}

// ---------------- premultiply: xin2 = bf16(om * cur_x) ----------------
__global__ __launch_bounds__(256) void k_premult(const float* __restrict__ cur_x,
                                                 const short* __restrict__ om_bf,
                                                 short* __restrict__ xin2) {
    int e = blockIdx.x * 256 + threadIdx.x;   // 2097152 exactly (8.39M/4)
    int flat = e << 2;
    int pix = flat & 16383;
    int b = flat >> 20;                        // flat >> 14 >> 6
    f32x4 xv = *(const f32x4*)&cur_x[flat];
    short4v ov = *(const short4v*)&om_bf[(b << 14) + pix];
    short4v res;
    #pragma unroll
    for (int k = 0; k < 4; ++k) res[k] = f2bf_s(xv[k] * bfb2f(ov[k]));
    *(short4v*)&xin2[flat] = res;
}

// ---------------- conv3 weight prep: 4 layers fp32 [64][64][3][3] -> bf16 wb3 ----------------
// per-layer layout [cc 2][dy 3][dx 3][o 64][c 32], layer stride 36864
__global__ __launch_bounds__(256) void k_prepw3(const float* __restrict__ w0,
                                                const float* __restrict__ w1,
                                                const float* __restrict__ w2,
                                                const float* __restrict__ w3,
                                                short* __restrict__ wb3) {
    int s = blockIdx.x * 256 + threadIdx.x;
    if (s >= 147456) return;
    int layer = s / 36864; int r = s - layer * 36864;
    const float* w = (layer == 0) ? w0 : (layer == 1) ? w1 : (layer == 2) ? w2 : w3;
    int o = r / 576; int rem = r - o * 576;
    int c = rem / 9; int t = rem - c * 9;
    int dy = t / 3, dx = t - dy * 3;
    int cc = c >> 5, cl = c & 31;
    wb3[layer * 36864 + (((cc * 3 + dy) * 3 + dx) * 64 + o) * 32 + cl] = f2bf_s(w[r]);
}

// ---------------- upconv weight prep (unchanged from round 4) ----------------
__global__ __launch_bounds__(256) void k_prepw(const float* __restrict__ w,
                                               short* __restrict__ wb) {
    int s = blockIdx.x * 256 + threadIdx.x;
    if (s >= 1605632) return;
    int O = s / 6272; int r = s - O * 6272;
    int C = r / 49;   int T = r - C * 49;
    int dy = T / 7, dx = T - dy * 7;
    int nt = O >> 6, o = O & 63;
    int cc = C >> 5, c = C & 31;
    int W = ((((nt * 4 + cc) * 7 + dy) * 7 + dx) * 64 + o) * 32 + c;
    wb[W] = f2bf_s(w[s]);
}

// ---------------- up-conv 7x7 MFMA + BN + ReLU + pixel_shuffle -> dep (bf16) ----------------
__global__ __launch_bounds__(256) void k_upconv_mfma(
    const float* __restrict__ x,      // [8,128,64,64]
    const short* __restrict__ wb,     // prepped weights
    const float* __restrict__ cb,     // [256]
    const float* __restrict__ bnp,    // [4,256]
    short* __restrict__ dep) {        // [8,64,128,128] bf16
    __shared__ __attribute__((aligned(16))) short s_in[308 * 40];
    __shared__ __attribute__((aligned(16))) short s_w[448 * 40];
    int tid = threadIdx.x;
    int wave = tid >> 6, lane = tid & 63;
    int q = lane >> 4, m = lane & 15;
    int mw = wave >> 1, nw = wave & 1;
    int ty0 = (blockIdx.x >> 2) * 8;
    int tx0 = (blockIdx.x & 3) * 16;
    int nt = blockIdx.y;
    int b = blockIdx.z;
    f32x4 acc[4][2];
    #pragma unroll
    for (int i = 0; i < 4; ++i)
        #pragma unroll
        for (int j = 0; j < 2; ++j)
            acc[i][j] = (f32x4){0.f, 0.f, 0.f, 0.f};
    const float* xb = x + ((long)(b * 128) << 12);
    for (int cc = 0; cc < 4; ++cc) {
        __syncthreads();
        for (int e = tid; e < 1232; e += 256) {
            int cq = e / 308; int cell = e - cq * 308;
            int yy = cell / 22, xx = cell - yy * 22;
            int gy = ty0 + yy - 3, gx = tx0 + xx - 3;
            float v[8];
            if ((unsigned)gy < 64u && (unsigned)gx < 64u) {
                const float* src = xb + (((cc * 32 + cq * 8)) << 12) + (gy << 6) + gx;
                #pragma unroll
                for (int j2 = 0; j2 < 8; ++j2) v[j2] = src[j2 << 12];
            } else {
                #pragma unroll
                for (int j2 = 0; j2 < 8; ++j2) v[j2] = 0.0f;
            }
            short8 pk;
            #pragma unroll
            for (int j2 = 0; j2 < 8; ++j2) pk[j2] = f2bf_s(v[j2]);
            *(short8*)&s_in[cell * 40 + cq * 8] = pk;
        }
        for (int dy = 0; dy < 7; ++dy) {
            __syncthreads();
            const short* wsl = wb + (((nt * 4 + cc) * 7 + dy) * 7) * 2048;
            for (int e = tid; e < 1792; e += 256) {
                int row = e >> 2, cq = e & 3;
                short8 pk = *(const short8*)&wsl[row * 32 + cq * 8];
                *(short8*)&s_w[row * 40 + cq * 8] = pk;
            }
            __syncthreads();
            #pragma unroll
            for (int dx = 0; dx < 7; ++dx) {
                short8 a[4], bf[2];
                #pragma unroll
                for (int i = 0; i < 4; ++i) {
                    int cell = (mw * 4 + i + dy) * 22 + (m + dx);
                    a[i] = *(const short8*)&s_in[cell * 40 + q * 8];
                }
                #pragma unroll
                for (int j = 0; j < 2; ++j) {
                    int row = dx * 64 + (nw * 2 + j) * 16 + m;
                    bf[j] = *(const short8*)&s_w[row * 40 + q * 8];
                }
                #pragma unroll
                for (int i = 0; i < 4; ++i)
                    #pragma unroll
                    for (int j = 0; j < 2; ++j)
                        acc[i][j] = __builtin_amdgcn_mfma_f32_16x16x32_bf16(
                            a[i], bf[j], acc[i][j], 0, 0, 0);
            }
        }
    }
    #pragma unroll
    for (int j = 0; j < 2; ++j) {
        int o = nt * 64 + (nw * 2 + j) * 16 + m;
        float g  = bnp[o],       bt = bnp[256 + o];
        float mn = bnp[512 + o], vv = bnp[768 + o];
        float scale = g * rsqrtf(vv + 1e-5f);
        float cbf = cb[o];
        int c = o >> 2, sbit = (o >> 1) & 1, tbit = o & 1;
        #pragma unroll
        for (int i = 0; i < 4; ++i) {
            int y = ty0 + mw * 4 + i;
            #pragma unroll
            for (int reg = 0; reg < 4; ++reg) {
                int xc = tx0 + q * 4 + reg;
                float val = (acc[i][j][reg] + cbf - mn) * scale + bt;
                val = fmaxf(val, 0.0f);
                dep[((b * 64 + c) << 14) + ((2 * y + sbit) << 7) + (2 * xc + tbit)] = f2bf_s(val);
            }
        }
    }
}

// ---------------- 3x3 conv 64->64 via MFMA, fused epilogues ----------------
// MODE 0: out = relu(bn(conv(xin) + cb));  MODE 1: out = dep + beta*(conv(xin) + cb)
// xin bf16 [8,64,128,128]; weights prepped [cc2][dy3][dx3][o64][c32] (global, L2-resident)
template <int MODE, bool OUTBF>
__global__ __launch_bounds__(256) void k_conv3m(
    const short* __restrict__ xin,
    const short* __restrict__ wl,
    const short* __restrict__ dep,   // bf16 residual (MODE 1)
    const float* __restrict__ cb,
    const float* __restrict__ bnp,
    const float* __restrict__ beta,
    void* __restrict__ out) {
    __shared__ __attribute__((aligned(16))) short s_in[180 * 40];  // 10x18 cells
    int tid = threadIdx.x;
    int wave = tid >> 6, lane = tid & 63;
    int q = lane >> 4, m = lane & 15;
    int mw = wave >> 1, nw = wave & 1;
    int ty0 = (blockIdx.x >> 3) * 8;      // 16 y-tiles of 8 rows
    int tx0 = (blockIdx.x & 7) * 16;      // 8 x-tiles of 16 cols
    int b = blockIdx.z;
    f32x4 acc[4][2];
    #pragma unroll
    for (int i = 0; i < 4; ++i)
        #pragma unroll
        for (int j = 0; j < 2; ++j)
            acc[i][j] = (f32x4){0.f, 0.f, 0.f, 0.f};
    const short* xb = xin + ((long)(b * 64) << 14);
    for (int cc = 0; cc < 2; ++cc) {
        __syncthreads();
        for (int e = tid; e < 720; e += 256) {
            int cq = e / 180; int cell = e - cq * 180;
            int yy = cell / 18, xx = cell - yy * 18;
            int gy = ty0 + yy - 1, gx = tx0 + xx - 1;
            short8 pk;
            if ((unsigned)gy < 128u && (unsigned)gx < 128u) {
                const short* src = xb + ((cc * 32 + cq * 8) << 14) + (gy << 7) + gx;
                #pragma unroll
                for (int j2 = 0; j2 < 8; ++j2) pk[j2] = src[j2 << 14];
            } else {
                #pragma unroll
                for (int j2 = 0; j2 < 8; ++j2) pk[j2] = 0;
            }
            *(short8*)&s_in[cell * 40 + cq * 8] = pk;
        }
        __syncthreads();
        #pragma unroll
        for (int dy = 0; dy < 3; ++dy) {
            #pragma unroll
            for (int dx = 0; dx < 3; ++dx) {
                const short* wp = wl + (((cc * 3 + dy) * 3 + dx) << 11);
                short8 bf[2];
                #pragma unroll
                for (int j = 0; j < 2; ++j)
                    bf[j] = *(const short8*)(wp + ((nw * 32 + j * 16 + m) << 5) + (q << 3));
                short8 a[4];
                #pragma unroll
                for (int i = 0; i < 4; ++i)
                    a[i] = *(const short8*)&s_in[((mw * 4 + i + dy) * 18 + m + dx) * 40 + q * 8];
                #pragma unroll
                for (int i = 0; i < 4; ++i)
                    #pragma unroll
                    for (int j = 0; j < 2; ++j)
                        acc[i][j] = __builtin_amdgcn_mfma_f32_16x16x32_bf16(
                            a[i], bf[j], acc[i][j], 0, 0, 0);
            }
        }
    }
    float betav = (MODE == 1) ? beta[0] : 0.0f;
    #pragma unroll
    for (int j = 0; j < 2; ++j) {
        int o = nw * 32 + j * 16 + m;
        float cbf = cb[o];
        float scale = 1.0f, shift = 0.0f;
        if (MODE == 0) {
            float g  = bnp[o],       bt = bnp[64 + o];
            float mm = bnp[128 + o], vv = bnp[192 + o];
            scale = g * rsqrtf(vv + 1e-5f);
            shift = bt - mm * scale;
        }
        #pragma unroll
        for (int i = 0; i < 4; ++i) {
            int y = ty0 + mw * 4 + i;
            int base = ((b * 64 + o) << 14) + (y << 7) + tx0 + q * 4;
            float vals[4];
            if (MODE == 1) {
                short4v dv = *(const short4v*)&dep[base];
                #pragma unroll
                for (int reg = 0; reg < 4; ++reg)
                    vals[reg] = bfb2f(dv[reg]) + betav * (acc[i][j][reg] + cbf);
            } else {
                #pragma unroll
                for (int reg = 0; reg < 4; ++reg)
                    vals[reg] = fmaxf((acc[i][j][reg] + cbf) * scale + shift, 0.0f);
            }
            if (OUTBF) {
                short4v sv;
                #pragma unroll
                for (int reg = 0; reg < 4; ++reg) sv[reg] = f2bf_s(vals[reg]);
                *(short4v*)((short*)out + base) = sv;
            } else {
                f32x4 fv;
                #pragma unroll
                for (int reg = 0; reg < 4; ++reg) fv[reg] = vals[reg];
                *(f32x4*)((float*)out + base) = fv;
            }
        }
    }
}

// ---------------- final 7x7 conv (64->1), fp32 in/out (unchanged) ----------------
__global__ __launch_bounds__(256) void k_outconv(
    const float* __restrict__ r,
    const float* __restrict__ w,
    const float* __restrict__ ob,
    float* __restrict__ out) {
    __shared__ float s_in[8][22][22];
    __shared__ float s_w[64 * 49];
    int tid = threadIdx.x;
    int ty = tid >> 4, tx = tid & 15;
    int ty0 = (blockIdx.x >> 3) << 4, tx0 = (blockIdx.x & 7) << 4;
    int b = blockIdx.z;
    for (int e = tid; e < 64 * 49; e += 256) s_w[e] = w[e];
    float acc = 0.0f;
    for (int c0 = 0; c0 < 64; c0 += 8) {
        __syncthreads();
        for (int e = tid; e < 8 * 484; e += 256) {
            int i = e / 484; int r2 = e - i * 484; int yy = r2 / 22; int xx = r2 - yy * 22;
            int gy = ty0 + yy - 3, gx = tx0 + xx - 3;
            float v = 0.0f;
            if ((unsigned)gy < 128u && (unsigned)gx < 128u)
                v = r[((b * 64 + c0 + i) << 14) + (gy << 7) + gx];
            s_in[i][yy][xx] = v;
        }
        __syncthreads();
        for (int i = 0; i < 8; ++i) {
            #pragma unroll
            for (int dy = 0; dy < 7; ++dy)
                #pragma unroll
                for (int dx = 0; dx < 7; ++dx)
                    acc = fmaf(s_in[i][ty + dy][tx + dx], s_w[(c0 + i) * 49 + dy * 7 + dx], acc);
        }
    }
    out[(b << 14) + ((ty0 + ty) << 7) + tx0 + tx] = acc + ob[0];
}

extern "C" void kernel_launch(void* const* d_in, const int* in_sizes, int n_in,
                              void* d_out, int out_size, void* d_ws, size_t ws_size,
                              hipStream_t stream) {
    const float* cur_x  = (const float*)d_in[0];
    const float* dep_x  = (const float*)d_in[1];
    const float* in_map = (const float*)d_in[2];
    const float* up_w   = (const float*)d_in[3];
    const float* up_b   = (const float*)d_in[4];
    const float* up_bn  = (const float*)d_in[5];
    const float* c2_w   = (const float*)d_in[6];
    const float* c2_b   = (const float*)d_in[7];
    const float* d1_w   = (const float*)d_in[8];
    const float* d1_b   = (const float*)d_in[9];
    const float* d1_bn  = (const float*)d_in[10];
    const float* d2_w   = (const float*)d_in[11];
    const float* d2_b   = (const float*)d_in[12];
    const float* d2_bn  = (const float*)d_in[13];
    const float* d3_w   = (const float*)d_in[14];
    const float* d3_b   = (const float*)d_in[15];
    const float* d3_bn  = (const float*)d_in[16];
    const float* out_w  = (const float*)d_in[17];
    const float* out_b  = (const float*)d_in[18];
    const float* beta   = (const float*)d_in[19];

    // Buffer plan (ws use = 16.8 MiB exactly, proven safe):
    //   A  = ws[0..16.8M) bf16      : xin2 (steps 2-6) then r2 (steps 8-9)
    //   B  = d_out[0..16.8M) bf16   : dep (5-6) then r1 (7-8)
    //   C  = d_out[16.8..33.5M) bf16: wb at head (4-5) then t (6-7)
    //   map region d_out[33.5..34M) : om_bf (1-2) -> wb3 (3-9) -> final map (10)
    //   r_out fp32 = d_out[0..33.5M): final r written by d3 (step 9)
    char* ob = (char*)d_out;
    float* r_out  = (float*)ob;
    short* A      = (short*)d_ws;
    short* B      = (short*)ob;
    short* C      = (short*)(ob + 16777216);
    short* wb     = C;                           // head of C, dead before t
    short* om_bf  = (short*)(ob + 33554432);
    short* wb3    = (short*)(ob + 33554432);     // overwrites om_bf after premult
    float* mapout = (float*)(ob + 33554432);

    // 1. maps -> om (bf16)
    k_maps<<<dim3(64, 1, 8), 256, 0, stream>>>(in_map, om_bf);
    // 2. xin2 = bf16(om * cur_x) -> A
    k_premult<<<8192, 256, 0, stream>>>(cur_x, om_bf, A);
    // 3. prep conv3 weights -> wb3 (om dead)
    k_prepw3<<<576, 256, 0, stream>>>(c2_w, d1_w, d2_w, d3_w, wb3);
    // 4. prep upconv weights -> wb (C head)
    k_prepw<<<6272, 256, 0, stream>>>(up_w, wb);
    // 5. dep = pixel_shuffle(relu(bn(conv7x7(dep_x)))) -> B (bf16)
    k_upconv_mfma<<<dim3(32, 4, 8), 256, 0, stream>>>(dep_x, wb, up_b, up_bn, B);
    // 6. t = dep + beta*(conv3(xin2) + c2_b) -> C (wb dead)
    k_conv3m<1, true><<<dim3(128, 1, 8), 256, 0, stream>>>(
        A, wb3 + 0 * 36864, B, c2_b, nullptr, beta, C);
    // 7. r1 -> B (dep dead)
    k_conv3m<0, true><<<dim3(128, 1, 8), 256, 0, stream>>>(
        C, wb3 + 1 * 36864, nullptr, d1_b, d1_bn, nullptr, B);
    // 8. r2 -> A (xin2 dead)
    k_conv3m<0, true><<<dim3(128, 1, 8), 256, 0, stream>>>(
        B, wb3 + 2 * 36864, nullptr, d2_b, d2_bn, nullptr, A);
    // 9. r (final, fp32) -> r_out (t/r1 dead; wb3 in map region untouched)
    k_conv3m<0, false><<<dim3(128, 1, 8), 256, 0, stream>>>(
        A, wb3 + 3 * 36864, nullptr, d3_b, d3_bn, nullptr, r_out);
    // 10. output_map = conv7x7(r) + out_b -> map region (wb3 dead)
    k_outconv<<<dim3(64, 1, 8), 256, 0, stream>>>(r_out, out_w, out_b, mapout);
}

// Round 6
// 498.851 us; speedup vs baseline: 5.0214x; 1.1457x over previous
//
#include <hip/hip_runtime.h>
#include <hip/hip_bf16.h>
#include <math.h>

static __device__ __forceinline__ float sigm(float x) { return 1.0f / (1.0f + expf(-x)); }

// fp32 -> bf16 bits, round-to-nearest-even
static __device__ __forceinline__ short f2bf_s(float f) {
    unsigned u = __float_as_uint(f);
    u += 0x7fffu + ((u >> 16) & 1u);
    return (short)(u >> 16);
}
// bf16 bits -> fp32
static __device__ __forceinline__ float bfb2f(short s) {
    return __uint_as_float(((unsigned)(unsigned short)s) << 16);
}

typedef __attribute__((ext_vector_type(8))) short short8;
typedef __attribute__((ext_vector_type(4))) short short4v;
typedef __attribute__((ext_vector_type(4))) float f32x4;

// ---------------- fused map pipeline -> om (bf16) ----------------
__global__ __launch_bounds__(256) void k_maps(const float* __restrict__ in_map,
                                              short* __restrict__ om_bf) {
    __shared__ float s_u[20][20];
    __shared__ float s_inc[18][18];
    int tid = threadIdx.x;
    int b = blockIdx.z;
    int ty0 = (blockIdx.x >> 3) << 4, tx0 = (blockIdx.x & 7) << 4;
    const float* p = in_map + (b << 12);
    const float s = 63.0f / 127.0f;
    for (int e = tid; e < 400; e += 256) {
        int yy = e / 20, xx = e % 20;
        int gy = ty0 + yy - 2, gx = tx0 + xx - 2;
        float v = 0.0f;
        if ((unsigned)gy < 128u && (unsigned)gx < 128u) {
            float cy = gy * s, cx = gx * s;
            int iy0 = (int)cy, ix0 = (int)cx;
            float wy = cy - (float)iy0, wx = cx - (float)ix0;
            int iy1 = min(iy0 + 1, 63), ix1 = min(ix0 + 1, 63);
            float v00 = p[(iy0 << 6) + ix0], v01 = p[(iy0 << 6) + ix1];
            float v10 = p[(iy1 << 6) + ix0], v11 = p[(iy1 << 6) + ix1];
            v = (1.0f - wy) * ((1.0f - wx) * v00 + wx * v01) +
                wy          * ((1.0f - wx) * v10 + wx * v11);
        }
        s_u[yy][xx] = v;
    }
    __syncthreads();
    for (int e = tid; e < 324; e += 256) {
        int yy = e / 18, xx = e % 18;
        int gy = ty0 + yy - 1, gx = tx0 + xx - 1;
        float val = -INFINITY;
        if ((unsigned)gy < 128u && (unsigned)gx < 128u) {
            float uc = s_u[yy + 1][xx + 1];
            float mx = -INFINITY;
            for (int dy = -1; dy <= 1; ++dy) {
                int ny = gy + dy; if ((unsigned)ny >= 128u) continue;
                for (int dx = -1; dx <= 1; ++dx) {
                    int nx = gx + dx; if ((unsigned)nx >= 128u) continue;
                    mx = fmaxf(mx, s_u[yy + 1 + dy][xx + 1 + dx]);
                }
            }
            val = sigm(mx) - sigm(uc);
        }
        s_inc[yy][xx] = val;
    }
    __syncthreads();
    int row = tid >> 4, col = tid & 15;
    int gy = ty0 + row, gx = tx0 + col;
    float mx = -INFINITY;
    #pragma unroll
    for (int dy = 0; dy < 3; ++dy)
        #pragma unroll
        for (int dx = 0; dx < 3; ++dx)
            mx = fmaxf(mx, s_inc[row + dy][col + dx]);
    float uc = s_u[row + 2][col + 2];
    float mn = INFINITY;
    for (int dy = -1; dy <= 1; ++dy) {
        int ny = gy + dy; if ((unsigned)ny >= 128u) continue;
        for (int dx = -1; dx <= 1; ++dx) {
            int nx = gx + dx; if ((unsigned)nx >= 128u) continue;
            mn = fminf(mn, s_u[row + 2 + dy][col + 2 + dx]);
        }
    }
    float inc2 = sigm(1.0f - mn) - sigm(1.0f - uc);
    om_bf[(b << 14) + (gy << 7) + gx] = f2bf_s(mx + inc2);
}

// ---------------- premultiply: xin2 = bf16(om * cur_x) ----------------
__global__ __launch_bounds__(256) void k_premult(const float* __restrict__ cur_x,
                                                 const short* __restrict__ om_bf,
                                                 short* __restrict__ xin2) {
    int e = blockIdx.x * 256 + threadIdx.x;
    int flat = e << 2;
    int pix = flat & 16383;
    int b = flat >> 20;
    f32x4 xv = *(const f32x4*)&cur_x[flat];
    short4v ov = *(const short4v*)&om_bf[(b << 14) + pix];
    short4v res;
    #pragma unroll
    for (int k = 0; k < 4; ++k) res[k] = f2bf_s(xv[k] * bfb2f(ov[k]));
    *(short4v*)&xin2[flat] = res;
}

// ---------------- conv3 weight prep ----------------
__global__ __launch_bounds__(256) void k_prepw3(const float* __restrict__ w0,
                                                const float* __restrict__ w1,
                                                const float* __restrict__ w2,
                                                const float* __restrict__ w3,
                                                short* __restrict__ wb3) {
    int s = blockIdx.x * 256 + threadIdx.x;
    if (s >= 147456) return;
    int layer = s / 36864; int r = s - layer * 36864;
    const float* w = (layer == 0) ? w0 : (layer == 1) ? w1 : (layer == 2) ? w2 : w3;
    int o = r / 576; int rem = r - o * 576;
    int c = rem / 9; int t = rem - c * 9;
    int dy = t / 3, dx = t - dy * 3;
    int cc = c >> 5, cl = c & 31;
    wb3[layer * 36864 + (((cc * 3 + dy) * 3 + dx) * 64 + o) * 32 + cl] = f2bf_s(w[r]);
}

// ---------------- upconv weight prep ----------------
__global__ __launch_bounds__(256) void k_prepw(const float* __restrict__ w,
                                               short* __restrict__ wb) {
    int s = blockIdx.x * 256 + threadIdx.x;
    if (s >= 1605632) return;
    int O = s / 6272; int r = s - O * 6272;
    int C = r / 49;   int T = r - C * 49;
    int dy = T / 7, dx = T - dy * 7;
    int nt = O >> 6, o = O & 63;
    int cc = C >> 5, c = C & 31;
    int W = ((((nt * 4 + cc) * 7 + dy) * 7 + dx) * 64 + o) * 32 + c;
    wb[W] = f2bf_s(w[s]);
}

// ---------------- up-conv 7x7 MFMA v3: B direct from global, no s_w ----------------
// Block: 4 waves (mw=wave), tile 16x16 px, all 64 oc of nt per wave (j=0..3).
// A from LDS (stride-40 layout, verified); B frags global_load_dwordx4, L1/L2-hit.
__global__ __launch_bounds__(256) void k_upconv_mfma(
    const float* __restrict__ x,      // [8,128,64,64]
    const short* __restrict__ wb,     // prepped [nt4][cc4][dy7][dx7][o64][c32]
    const float* __restrict__ cb,     // [256]
    const float* __restrict__ bnp,    // [4,256]
    short* __restrict__ dep) {        // [8,64,128,128] bf16
    __shared__ __attribute__((aligned(16))) short s_in[484 * 40];  // 22x22 cells
    int tid = threadIdx.x;
    int mw = tid >> 6, lane = tid & 63;
    int q = lane >> 4, m = lane & 15;
    int ty0 = (blockIdx.x >> 2) * 16;     // 4 y-tiles of 16 rows
    int tx0 = (blockIdx.x & 3) * 16;      // 4 x-tiles of 16 cols
    int nt = blockIdx.y;
    int b = blockIdx.z;
    f32x4 acc[4][4];
    #pragma unroll
    for (int i = 0; i < 4; ++i)
        #pragma unroll
        for (int j = 0; j < 4; ++j)
            acc[i][j] = (f32x4){0.f, 0.f, 0.f, 0.f};
    const float* xb = x + ((long)(b * 128) << 12);
    for (int cc = 0; cc < 4; ++cc) {
        __syncthreads();   // previous-iter readers of s_in done
        for (int e = tid; e < 1936; e += 256) {
            int cq = e / 484; int cell = e - cq * 484;
            int yy = cell / 22, xx = cell - yy * 22;
            int gy = ty0 + yy - 3, gx = tx0 + xx - 3;
            float v[8];
            if ((unsigned)gy < 64u && (unsigned)gx < 64u) {
                const float* src = xb + ((cc * 32 + cq * 8) << 12) + (gy << 6) + gx;
                #pragma unroll
                for (int j2 = 0; j2 < 8; ++j2) v[j2] = src[j2 << 12];
            } else {
                #pragma unroll
                for (int j2 = 0; j2 < 8; ++j2) v[j2] = 0.0f;
            }
            short8 pk;
            #pragma unroll
            for (int j2 = 0; j2 < 8; ++j2) pk[j2] = f2bf_s(v[j2]);
            *(short8*)&s_in[cell * 40 + cq * 8] = pk;
        }
        __syncthreads();
        for (int dy = 0; dy < 7; ++dy) {
            const short* wsl = wb + (((nt * 4 + cc) * 7 + dy) * 7) * 2048;
            #pragma unroll
            for (int dx = 0; dx < 7; ++dx) {
                short8 bf[4];
                #pragma unroll
                for (int j = 0; j < 4; ++j)
                    bf[j] = *(const short8*)(wsl + (dx << 11) + ((j * 16 + m) << 5) + (q << 3));
                short8 a[4];
                #pragma unroll
                for (int i = 0; i < 4; ++i)
                    a[i] = *(const short8*)&s_in[((mw * 4 + i + dy) * 22 + m + dx) * 40 + q * 8];
                #pragma unroll
                for (int i = 0; i < 4; ++i)
                    #pragma unroll
                    for (int j = 0; j < 4; ++j)
                        acc[i][j] = __builtin_amdgcn_mfma_f32_16x16x32_bf16(
                            a[i], bf[j], acc[i][j], 0, 0, 0);
            }
        }
    }
    // epilogue: bias + BN + ReLU + pixel-shuffle scatter (bf16)
    #pragma unroll
    for (int j = 0; j < 4; ++j) {
        int o = nt * 64 + j * 16 + m;
        float g  = bnp[o],       bt = bnp[256 + o];
        float mn = bnp[512 + o], vv = bnp[768 + o];
        float scale = g * rsqrtf(vv + 1e-5f);
        float cbf = cb[o];
        int c = o >> 2, sbit = (o >> 1) & 1, tbit = o & 1;
        #pragma unroll
        for (int i = 0; i < 4; ++i) {
            int y = ty0 + mw * 4 + i;
            #pragma unroll
            for (int reg = 0; reg < 4; ++reg) {
                int xc = tx0 + q * 4 + reg;
                float val = (acc[i][j][reg] + cbf - mn) * scale + bt;
                val = fmaxf(val, 0.0f);
                dep[((b * 64 + c) << 14) + ((2 * y + sbit) << 7) + (2 * xc + tbit)] = f2bf_s(val);
            }
        }
    }
}

// ---------------- 3x3 conv 64->64 via MFMA (unchanged, verified) ----------------
template <int MODE, bool OUTBF>
__global__ __launch_bounds__(256) void k_conv3m(
    const short* __restrict__ xin,
    const short* __restrict__ wl,
    const short* __restrict__ dep,
    const float* __restrict__ cb,
    const float* __restrict__ bnp,
    const float* __restrict__ beta,
    void* __restrict__ out) {
    __shared__ __attribute__((aligned(16))) short s_in[180 * 40];
    int tid = threadIdx.x;
    int wave = tid >> 6, lane = tid & 63;
    int q = lane >> 4, m = lane & 15;
    int mw = wave >> 1, nw = wave & 1;
    int ty0 = (blockIdx.x >> 3) * 8;
    int tx0 = (blockIdx.x & 7) * 16;
    int b = blockIdx.z;
    f32x4 acc[4][2];
    #pragma unroll
    for (int i = 0; i < 4; ++i)
        #pragma unroll
        for (int j = 0; j < 2; ++j)
            acc[i][j] = (f32x4){0.f, 0.f, 0.f, 0.f};
    const short* xb = xin + ((long)(b * 64) << 14);
    for (int cc = 0; cc < 2; ++cc) {
        __syncthreads();
        for (int e = tid; e < 720; e += 256) {
            int cq = e / 180; int cell = e - cq * 180;
            int yy = cell / 18, xx = cell - yy * 18;
            int gy = ty0 + yy - 1, gx = tx0 + xx - 1;
            short8 pk;
            if ((unsigned)gy < 128u && (unsigned)gx < 128u) {
                const short* src = xb + ((cc * 32 + cq * 8) << 14) + (gy << 7) + gx;
                #pragma unroll
                for (int j2 = 0; j2 < 8; ++j2) pk[j2] = src[j2 << 14];
            } else {
                #pragma unroll
                for (int j2 = 0; j2 < 8; ++j2) pk[j2] = 0;
            }
            *(short8*)&s_in[cell * 40 + cq * 8] = pk;
        }
        __syncthreads();
        #pragma unroll
        for (int dy = 0; dy < 3; ++dy) {
            #pragma unroll
            for (int dx = 0; dx < 3; ++dx) {
                const short* wp = wl + (((cc * 3 + dy) * 3 + dx) << 11);
                short8 bf[2];
                #pragma unroll
                for (int j = 0; j < 2; ++j)
                    bf[j] = *(const short8*)(wp + ((nw * 32 + j * 16 + m) << 5) + (q << 3));
                short8 a[4];
                #pragma unroll
                for (int i = 0; i < 4; ++i)
                    a[i] = *(const short8*)&s_in[((mw * 4 + i + dy) * 18 + m + dx) * 40 + q * 8];
                #pragma unroll
                for (int i = 0; i < 4; ++i)
                    #pragma unroll
                    for (int j = 0; j < 2; ++j)
                        acc[i][j] = __builtin_amdgcn_mfma_f32_16x16x32_bf16(
                            a[i], bf[j], acc[i][j], 0, 0, 0);
            }
        }
    }
    float betav = (MODE == 1) ? beta[0] : 0.0f;
    #pragma unroll
    for (int j = 0; j < 2; ++j) {
        int o = nw * 32 + j * 16 + m;
        float cbf = cb[o];
        float scale = 1.0f, shift = 0.0f;
        if (MODE == 0) {
            float g  = bnp[o],       bt = bnp[64 + o];
            float mm = bnp[128 + o], vv = bnp[192 + o];
            scale = g * rsqrtf(vv + 1e-5f);
            shift = bt - mm * scale;
        }
        #pragma unroll
        for (int i = 0; i < 4; ++i) {
            int y = ty0 + mw * 4 + i;
            int base = ((b * 64 + o) << 14) + (y << 7) + tx0 + q * 4;
            float vals[4];
            if (MODE == 1) {
                short4v dv = *(const short4v*)&dep[base];
                #pragma unroll
                for (int reg = 0; reg < 4; ++reg)
                    vals[reg] = bfb2f(dv[reg]) + betav * (acc[i][j][reg] + cbf);
            } else {
                #pragma unroll
                for (int reg = 0; reg < 4; ++reg)
                    vals[reg] = fmaxf((acc[i][j][reg] + cbf) * scale + shift, 0.0f);
            }
            if (OUTBF) {
                short4v sv;
                #pragma unroll
                for (int reg = 0; reg < 4; ++reg) sv[reg] = f2bf_s(vals[reg]);
                *(short4v*)((short*)out + base) = sv;
            } else {
                f32x4 fv;
                #pragma unroll
                for (int reg = 0; reg < 4; ++reg) fv[reg] = vals[reg];
                *(f32x4*)((float*)out + base) = fv;
            }
        }
    }
}

// ---------------- final 7x7 conv (64->1), fp32 (unchanged) ----------------
__global__ __launch_bounds__(256) void k_outconv(
    const float* __restrict__ r,
    const float* __restrict__ w,
    const float* __restrict__ ob,
    float* __restrict__ out) {
    __shared__ float s_in[8][22][22];
    __shared__ float s_w[64 * 49];
    int tid = threadIdx.x;
    int ty = tid >> 4, tx = tid & 15;
    int ty0 = (blockIdx.x >> 3) << 4, tx0 = (blockIdx.x & 7) << 4;
    int b = blockIdx.z;
    for (int e = tid; e < 64 * 49; e += 256) s_w[e] = w[e];
    float acc = 0.0f;
    for (int c0 = 0; c0 < 64; c0 += 8) {
        __syncthreads();
        for (int e = tid; e < 8 * 484; e += 256) {
            int i = e / 484; int r2 = e - i * 484; int yy = r2 / 22; int xx = r2 - yy * 22;
            int gy = ty0 + yy - 3, gx = tx0 + xx - 3;
            float v = 0.0f;
            if ((unsigned)gy < 128u && (unsigned)gx < 128u)
                v = r[((b * 64 + c0 + i) << 14) + (gy << 7) + gx];
            s_in[i][yy][xx] = v;
        }
        __syncthreads();
        for (int i = 0; i < 8; ++i) {
            #pragma unroll
            for (int dy = 0; dy < 7; ++dy)
                #pragma unroll
                for (int dx = 0; dx < 7; ++dx)
                    acc = fmaf(s_in[i][ty + dy][tx + dx], s_w[(c0 + i) * 49 + dy * 7 + dx], acc);
        }
    }
    out[(b << 14) + ((ty0 + ty) << 7) + tx0 + tx] = acc + ob[0];
}

extern "C" void kernel_launch(void* const* d_in, const int* in_sizes, int n_in,
                              void* d_out, int out_size, void* d_ws, size_t ws_size,
                              hipStream_t stream) {
    const float* cur_x  = (const float*)d_in[0];
    const float* dep_x  = (const float*)d_in[1];
    const float* in_map = (const float*)d_in[2];
    const float* up_w   = (const float*)d_in[3];
    const float* up_b   = (const float*)d_in[4];
    const float* up_bn  = (const float*)d_in[5];
    const float* c2_w   = (const float*)d_in[6];
    const float* c2_b   = (const float*)d_in[7];
    const float* d1_w   = (const float*)d_in[8];
    const float* d1_b   = (const float*)d_in[9];
    const float* d1_bn  = (const float*)d_in[10];
    const float* d2_w   = (const float*)d_in[11];
    const float* d2_b   = (const float*)d_in[12];
    const float* d2_bn  = (const float*)d_in[13];
    const float* d3_w   = (const float*)d_in[14];
    const float* d3_b   = (const float*)d_in[15];
    const float* d3_bn  = (const float*)d_in[16];
    const float* out_w  = (const float*)d_in[17];
    const float* out_b  = (const float*)d_in[18];
    const float* beta   = (const float*)d_in[19];

    // Buffer plan (ws use = 16.8 MiB, proven safe):
    //   A  = ws[0..16.8M) bf16      : xin2 (steps 2-6) then r2 (steps 8-9)
    //   B  = d_out[0..16.8M) bf16   : dep (5-6) then r1 (7-8)
    //   C  = d_out[16.8..33.5M) bf16: wb at head (4-5) then t (6-7)
    //   map region d_out[33.5..34M) : om_bf (1-2) -> wb3 (3-9) -> final map (10)
    //   r_out fp32 = d_out[0..33.5M): final r written by d3 (step 9)
    char* ob = (char*)d_out;
    float* r_out  = (float*)ob;
    short* A      = (short*)d_ws;
    short* B      = (short*)ob;
    short* C      = (short*)(ob + 16777216);
    short* wb     = C;
    short* om_bf  = (short*)(ob + 33554432);
    short* wb3    = (short*)(ob + 33554432);
    float* mapout = (float*)(ob + 33554432);

    k_maps<<<dim3(64, 1, 8), 256, 0, stream>>>(in_map, om_bf);
    k_premult<<<8192, 256, 0, stream>>>(cur_x, om_bf, A);
    k_prepw3<<<576, 256, 0, stream>>>(c2_w, d1_w, d2_w, d3_w, wb3);
    k_prepw<<<6272, 256, 0, stream>>>(up_w, wb);
    k_upconv_mfma<<<dim3(16, 4, 8), 256, 0, stream>>>(dep_x, wb, up_b, up_bn, B);
    k_conv3m<1, true><<<dim3(128, 1, 8), 256, 0, stream>>>(
        A, wb3 + 0 * 36864, B, c2_b, nullptr, beta, C);
    k_conv3m<0, true><<<dim3(128, 1, 8), 256, 0, stream>>>(
        C, wb3 + 1 * 36864, nullptr, d1_b, d1_bn, nullptr, B);
    k_conv3m<0, true><<<dim3(128, 1, 8), 256, 0, stream>>>(
        B, wb3 + 2 * 36864, nullptr, d2_b, d2_bn, nullptr, A);
    k_conv3m<0, false><<<dim3(128, 1, 8), 256, 0, stream>>>(
        A, wb3 + 3 * 36864, nullptr, d3_b, d3_bn, nullptr, r_out);
    k_outconv<<<dim3(64, 1, 8), 256, 0, stream>>>(r_out, out_w, out_b, mapout);
}